// Round 13
// baseline (50.976 us; speedup 1.0000x reference)
//
#include <hip/hip_runtime.h>
#include <hip/hip_bf16.h>
#include <stdint.h>

#define M_DIM 128
#define N_DIM 8192
#define K_DIM 8192
#define KP    4096      // packed int32 per weight row
#define NGRP  64
#define KSPLIT 8
#define NSTEPS 16       // 16 steps x 64 k per block (K/KSPLIT = 1024)
#define BK    64

typedef __attribute__((ext_vector_type(8))) short bf16x8;
typedef __attribute__((ext_vector_type(4))) float f32x4;

__device__ __forceinline__ unsigned short f2bf(float f) {
  unsigned int u = __float_as_uint(f);
  return (unsigned short)((u + 0x7fffu + ((u >> 16) & 1u)) >> 16);
}

__global__ void xcast_kernel(const float* __restrict__ x, unsigned short* __restrict__ xb) {
  int idx = (blockIdx.x * blockDim.x + threadIdx.x) * 8;
  const float4* xp = (const float4*)(x + idx);
  float4 a = xp[0], b = xp[1];
  uint4 o;
  o.x = (unsigned)f2bf(a.x) | ((unsigned)f2bf(a.y) << 16);
  o.y = (unsigned)f2bf(a.z) | ((unsigned)f2bf(a.w) << 16);
  o.z = (unsigned)f2bf(b.x) | ((unsigned)f2bf(b.y) << 16);
  o.w = (unsigned)f2bf(b.z) | ((unsigned)f2bf(b.w) << 16);
  *(uint4*)(xb + idx) = o;
}

// R10 kernel with ONE change: k-interleaved ksplit mapping. Block ks, step t
// consumes global 64k-chunk c = 16*(t>>1) + 2*ks + (t&1), so the 8 co-resident
// ks-blocks of an n-tile read a CONTIGUOUS 2KB window of each weight row at
// the same phase (DRAM page sharing), instead of windows 2KB apart.
// Scale group g = 8*(t>>1) + ks (uniform across each step pair).
__global__ __launch_bounds__(256, 2)
void gemm_kernel(const unsigned short* __restrict__ xb,
                 const int* __restrict__ wq,
                 const float* __restrict__ scale,
                 const float* __restrict__ zpt,
                 unsigned short* __restrict__ partial)
{
  __shared__ uint4 xtile[2][1024];   // 2 x 16 KB (128 rows x 8 chunks, swizzled)
  __shared__ uint4 wtile[2][1024];   // 2 x 16 KB raw int32 (128 rows x 8 chunks)

  const int tid = threadIdx.x;
  const int l   = tid & 63;
  const int w   = tid >> 6;
  const int l15 = l & 15;
  const int lk  = l >> 4;            // 0..3
  const int n0  = blockIdx.x * 128;
  const int ks  = blockIdx.y;

  const int r0 = n0 + w * 32 + l15;  // lane's two weight rows (B-frag cols)
  const int r1 = r0 + 16;

  // ---- scale/zp preload: stride-8 gather (g = 8u + ks, u = 0..7) ----
  float s0v[8], z0v[8], s1v[8], z1v[8];
  #pragma unroll
  for (int u = 0; u < 8; ++u) {
    s0v[u] = scale[r0 * NGRP + 8 * u + ks];
    z0v[u] = zpt  [r0 * NGRP + 8 * u + ks];
    s1v[u] = scale[r1 * NGRP + 8 * u + ks];
    z1v[u] = zpt  [r1 * NGRP + 8 * u + ks];
  }

  // stage x+W chunk for step t into buffer nb: 4 x-instrs + 4 W-instrs per wave
  auto STAGE = [&](int t, int nb) {
    const int c = 16 * (t >> 1) + 2 * ks + (t & 1);   // global 64k-chunk index
    #pragma unroll
    for (int i = 0; i < 4; ++i) {                 // x: 16 KB, rows 0..127
      int ci = i * 256 + tid;
      int row = ci >> 3, q = (ci & 7) ^ (row & 7); // inverse swizzle on source
      const unsigned short* src = xb + (size_t)row * K_DIM + c * 64 + q * 8;
      uint4* dst = &xtile[nb][i * 256 + w * 64];  // wave-uniform base
      __builtin_amdgcn_global_load_lds(
          (__attribute__((address_space(1))) void*)(void*)src,
          (__attribute__((address_space(3))) void*)(void*)dst, 16, 0, 0);
    }
    #pragma unroll
    for (int i = 0; i < 4; ++i) {                 // W raw: 16 KB (128 rows x 128 B)
      int ci = i * 256 + tid;
      int row = ci >> 3, q = (ci & 7) ^ (row & 7);
      const int* src = wq + (size_t)(n0 + row) * KP + c * 32 + q * 4;
      uint4* dst = &wtile[nb][i * 256 + w * 64];
      __builtin_amdgcn_global_load_lds(
          (__attribute__((address_space(1))) void*)(void*)src,
          (__attribute__((address_space(3))) void*)(void*)dst, 16, 0, 0);
    }
  };

  f32x4 acc[8][2];
  #pragma unroll
  for (int mi = 0; mi < 8; ++mi)
    #pragma unroll
    for (int ni = 0; ni < 2; ++ni) {
      f32x4 z = {0.f, 0.f, 0.f, 0.f};
      acc[mi][ni] = z;
    }

  // prologue: stages in flight, then derive scale regs (waits scales only)
  STAGE(0, 0);
  STAGE(1, 1);
  float scs0[8], scs1[8], nzs0[8], nzs1[8];
  #pragma unroll
  for (int u = 0; u < 8; ++u) {
    scs0[u] = s0v[u]; nzs0[u] = -z0v[u] * s0v[u];
    scs1[u] = s1v[u]; nzs1[u] = -z1v[u] * s1v[u];
  }

  const int wrow0 = w * 32 + l15;          // local W rows in the 128-row tile
  const int wrow1 = wrow0 + 16;

  #pragma unroll
  for (int t = 0; t < NSTEPS; ++t) {
    // retire stage(t) exactly (keep stage(t+1)'s 8 in flight), then sync
    asm volatile("s_waitcnt vmcnt(8)" ::: "memory");
    __builtin_amdgcn_s_barrier();

    const int cb = t & 1;
    const float sc[2] = {scs0[t >> 1], scs1[t >> 1]};   // static after unroll
    const float nz[2] = {nzs0[t >> 1], nzs1[t >> 1]};

    #pragma unroll
    for (int kk = 0; kk < 2; ++kk) {
      const int q = kk * 4 + lk;
      uint4 av[8];
      #pragma unroll
      for (int mi = 0; mi < 8; ++mi) {
        int r = mi * 16 + l15;
        av[mi] = xtile[cb][r * 8 + (q ^ (r & 7))];
      }
      uint4 pw[2];
      pw[0] = wtile[cb][wrow0 * 8 + (q ^ (wrow0 & 7))];  // 4 ints = lane's 8 nibbles
      pw[1] = wtile[cb][wrow1 * 8 + (q ^ (wrow1 & 7))];
      uint4 bq[2];
      #pragma unroll
      for (int ni = 0; ni < 2; ++ni) {
        int v4[4] = {(int)pw[ni].x, (int)pw[ni].y, (int)pw[ni].z, (int)pw[ni].w};
        unsigned words[4];
        #pragma unroll
        for (int j = 0; j < 4; ++j) {
          int hi = (v4[j] << 24) >> 28;      // bits 7:4 -> k even (proven)
          int lo = (v4[j] << 28) >> 28;      // bits 3:0 -> k odd
          float fh = fmaf((float)hi, sc[ni], nz[ni]);
          float fl = fmaf((float)lo, sc[ni], nz[ni]);
          asm("v_cvt_pk_bf16_f32 %0, %1, %2" : "=v"(words[j]) : "v"(fh), "v"(fl));
        }
        uint4 o; o.x = words[0]; o.y = words[1]; o.z = words[2]; o.w = words[3];
        bq[ni] = o;
      }
      #pragma unroll
      for (int mi = 0; mi < 8; ++mi)
        #pragma unroll
        for (int ni = 0; ni < 2; ++ni)
          acc[mi][ni] = __builtin_amdgcn_mfma_f32_16x16x32_bf16(
              __builtin_bit_cast(bf16x8, av[mi]),
              __builtin_bit_cast(bf16x8, bq[ni]),
              acc[mi][ni], 0, 0, 0);
    }

    // WAR fence for buffer t&1, then refill it (count-uniform tail restage)
    __builtin_amdgcn_s_barrier();
    STAGE(t + 2 < NSTEPS ? t + 2 : NSTEPS - 1, t & 1);
  }
  asm volatile("s_waitcnt vmcnt(0)" ::: "memory");  // drain tail stages

  // epilogue: bf16 partial [ks][s][o] (R10-verbatim)
  unsigned short* p = partial + (size_t)ks * (M_DIM * N_DIM);
  #pragma unroll
  for (int mi = 0; mi < 8; ++mi)
    #pragma unroll
    for (int ni = 0; ni < 2; ++ni) {
      int col = n0 + w * 32 + ni * 16 + l15;
      int rowb = mi * 16 + lk * 4;
      #pragma unroll
      for (int j = 0; j < 4; ++j)
        p[(size_t)(rowb + j) * N_DIM + col] = f2bf(acc[mi][ni][j]);
    }
}

// reduce over ksplit + bias (R10-verbatim)
__global__ void reduce_kernel(const unsigned short* __restrict__ part,
                              const float* __restrict__ bias,
                              float* __restrict__ out) {
  int idx = (blockIdx.x * blockDim.x + threadIdx.x) * 8;
  float s[8];
  #pragma unroll
  for (int j = 0; j < 8; ++j) s[j] = 0.f;
  #pragma unroll
  for (int k = 0; k < KSPLIT; ++k) {
    uint4 v = *(const uint4*)(part + (size_t)k * (M_DIM * N_DIM) + idx);
    unsigned ws[4] = {v.x, v.y, v.z, v.w};
    #pragma unroll
    for (int j = 0; j < 4; ++j) {
      s[2 * j]     += __uint_as_float((ws[j] & 0xffffu) << 16);
      s[2 * j + 1] += __uint_as_float(ws[j] & 0xffff0000u);
    }
  }
  int col = idx & (N_DIM - 1);
  float4 b0 = *(const float4*)(bias + col);
  float4 b1 = *(const float4*)(bias + col + 4);
  float4 o0, o1;
  o0.x = s[0] + b0.x; o0.y = s[1] + b0.y; o0.z = s[2] + b0.z; o0.w = s[3] + b0.w;
  o1.x = s[4] + b1.x; o1.y = s[5] + b1.y; o1.z = s[6] + b1.z; o1.w = s[7] + b1.w;
  *(float4*)(out + idx) = o0;
  *(float4*)(out + idx + 4) = o1;
}

extern "C" void kernel_launch(void* const* d_in, const int* in_sizes, int n_in,
                              void* d_out, int out_size, void* d_ws, size_t ws_size,
                              hipStream_t stream) {
  const float* x     = (const float*)d_in[0];
  const int*   wq    = (const int*)d_in[1];
  const float* scale = (const float*)d_in[2];
  const float* zpt   = (const float*)d_in[3];
  const float* bias  = (const float*)d_in[4];
  float* out = (float*)d_out;

  unsigned short* xb = (unsigned short*)d_ws;
  const size_t xbytes = (size_t)M_DIM * K_DIM * 2;                   // 2 MiB
  unsigned short* partial = (unsigned short*)((char*)d_ws + xbytes); // 16 MiB bf16

  xcast_kernel<<<(M_DIM * K_DIM) / (256 * 8), 256, 0, stream>>>(x, xb);
  gemm_kernel<<<dim3(N_DIM / 128, KSPLIT), 256, 0, stream>>>(
      xb, wq, scale, zpt, partial);
  reduce_kernel<<<(M_DIM * N_DIM) / (256 * 8), 256, 0, stream>>>(
      partial, bias, out);
}